// Round 8
// baseline (90.989 us; speedup 1.0000x reference)
//
#include <hip/hip_runtime.h>

#define NB   8
#define CIN  32
#define HH   28
#define WW   28
#define OC   64
#define HWSZ (HH*WW)            // 784
#define TOTAL (NB*OC*HWSZ)      // 401408
#define CNT  (NB*HWSZ)          // 6272 elements per channel for BN stats

#define KH   16                 // input channels per k-half
#define TROWS 4
#define TCOLS 32                // padded to 32 -> shift indexing, imm ds offsets
#define TSZ  (KH*TROWS*TCOLS)   // 2048 floats = 8 KB LDS

#define CPW  2                  // output channels per wave (4 waves -> 8 ch/block)
// grid: n(8) x rowpair(14) x chgrp(8) x khalf(2) = 1792 blocks, 7168 waves

__device__ __forceinline__ float rl(float v, int l) {
    return __int_as_float(__builtin_amdgcn_readlane(__float_as_int(v), l));
}

__global__ __launch_bounds__(256) void adder_kernel(
    const float* __restrict__ x, const float* __restrict__ Wt,
    float* __restrict__ raw01)   // raw01 = two TOTAL-sized partial buffers
{
    __shared__ float xs[TSZ];
    const int t     = threadIdx.x;
    const int bid   = blockIdx.x;
    const int khalf = bid & 1;
    const int chgrp = (bid >> 1) & 7;
    const int rp    = (bid >> 4) % 14;
    const int n     = bid / (16 * 14);
    const int h0    = rp * 2;
    const int c0    = khalf * KH;

    const int lane  = t & 63;
    const int g     = __builtin_amdgcn_readfirstlane(t >> 6); // wave id, uniform
    const int o_base = chgrp*8 + g*CPW;

    // ---- per-wave weight preload: 2 ch x 144 floats = 288 -> 5 VGPRs/lane ----
    // flattened idx = oo*144 + k*9 + j ; reg = idx>>6, lane = idx&63
    float vw[5];
    #pragma unroll
    for (int r = 0; r < 5; ++r) {
        int gidx = r*64 + lane;
        if (gidx > 287) gidx = 287;                 // clamp -> in-bounds
        const int oo  = gidx / 144;
        const int rem = gidx % 144;
        vw[r] = Wt[(o_base + oo)*(CIN*9) + khalf*144 + rem];
    }

    // ---- stage x strip: channels c0..c0+15, rows h0-1..h0+2, cols -1..30 ----
    #pragma unroll
    for (int i = t; i < TSZ; i += 256) {   // 8 exact iterations
        int cc  = i >> 7;          // /128
        int r   = (i >> 5) & 3;    // /32 % 4
        int col = i & 31;
        int hh  = h0 - 1 + r;
        int ww  = col - 1;
        float v = 0.0f;
        if (hh >= 0 && hh < HH && (unsigned)ww < (unsigned)WW)
            v = x[((n*CIN + (c0+cc))*HH + hh)*WW + ww];
        xs[i] = v;
    }
    __syncthreads();

    const bool valid = lane < 56;                 // 2 rows x 28 cols
    const int p     = valid ? lane : 0;
    const int pr    = p / WW;
    const int pw    = p % WW;
    const int b0    = pr*TCOLS + pw;

    float acc0 = 0.0f, acc1 = 0.0f;

    // 16 cc per wave: 9 ds_reads feed 2ch*18 = 36 arith; weights via
    // compile-time readlane -> DS-only lgkm traffic in the loop.
    #pragma unroll
    for (int k = 0; k < KH; ++k) {
        float xr[9];
        #pragma unroll
        for (int dr = 0; dr < 3; ++dr)
            #pragma unroll
            for (int dc = 0; dc < 3; ++dc)
                xr[dr*3+dc] = xs[(k << 7) + b0 + (dr << 5) + dc];
        #pragma unroll
        for (int j = 0; j < 9; ++j) {
            const int e0 = k*9 + j;               // ch 0: 0..143, compile-time
            const int e1 = 144 + k*9 + j;         // ch 1: 144..287
            acc0 += __builtin_fabsf(xr[j] - rl(vw[e0 >> 6], e0 & 63));
            acc1 += __builtin_fabsf(xr[j] - rl(vw[e1 >> 6], e1 & 63));
        }
    }

    // ---- write negated partial sums for this k-half ----
    if (valid) {
        float* rawh = raw01 + khalf * TOTAL;
        const int base = (h0 + pr)*WW + pw;
        rawh[(n*OC + o_base    )*HWSZ + base] = -acc0;
        rawh[(n*OC + o_base + 1)*HWSZ + base] = -acc1;
    }
}

// one block per output channel: combine halves, reduce sum/sumsq (double),
// emit per-channel scale/shift
__global__ __launch_bounds__(256) void stats_kernel(
    const float* __restrict__ raw01,
    const float* __restrict__ gamma, const float* __restrict__ beta,
    float* __restrict__ sc)
{
    const int o = blockIdx.x;
    const int t = threadIdx.x;
    const float4* r0 = (const float4*)raw01;
    const float4* r1 = (const float4*)(raw01 + TOTAL);
    double s = 0.0, s2 = 0.0;
    for (int i4 = t; i4 < CNT/4; i4 += 256) {     // 1568 float4s per channel
        int nn  = i4 / (HWSZ/4);
        int pos = i4 % (HWSZ/4);
        int idx = (nn*OC + o)*(HWSZ/4) + pos;
        float4 a = r0[idx];
        float4 b = r1[idx];
        float vx = a.x + b.x, vy = a.y + b.y, vz = a.z + b.z, vw = a.w + b.w;
        s  += (double)vx + (double)vy + (double)vz + (double)vw;
        s2 += (double)vx*vx + (double)vy*vy + (double)vz*vz + (double)vw*vw;
    }
    #pragma unroll
    for (int off = 32; off >= 1; off >>= 1) {
        s  += __shfl_xor(s,  off, 64);
        s2 += __shfl_xor(s2, off, 64);
    }
    __shared__ double ls[4], ls2[4];
    const int lane = t & 63, w = t >> 6;
    if (lane == 0) { ls[w] = s; ls2[w] = s2; }
    __syncthreads();
    if (t == 0) {
        double S  = ls[0] + ls[1] + ls[2] + ls[3];
        double S2 = ls2[0] + ls2[1] + ls2[2] + ls2[3];
        double mean = S * (1.0 / CNT);
        double var  = S2 * (1.0 / CNT) - mean * mean;
        double inv  = 1.0 / sqrt(var + 1e-5);
        double scl  = (double)gamma[o] * inv;
        sc[o]       = (float)scl;
        sc[64 + o]  = (float)((double)beta[o] - mean * scl);
    }
}

// y = (r0+r1)*sc[o] + sh[o], float4-vectorized
__global__ __launch_bounds__(256) void bn_kernel(
    const float* __restrict__ raw01, const float* __restrict__ sc,
    float* __restrict__ out)
{
    int i4 = blockIdx.x * 256 + threadIdx.x;   // float4 index
    if (i4 >= TOTAL/4) return;
    int o = (i4 / (HWSZ/4)) & (OC - 1);
    float s = sc[o];
    float b = sc[64 + o];
    float4 a0 = ((const float4*)raw01)[i4];
    float4 a1 = ((const float4*)(raw01 + TOTAL))[i4];
    float4 v;
    v.x = (a0.x + a1.x) * s + b;
    v.y = (a0.y + a1.y) * s + b;
    v.z = (a0.z + a1.z) * s + b;
    v.w = (a0.w + a1.w) * s + b;
    ((float4*)out)[i4] = v;
}

extern "C" void kernel_launch(void* const* d_in, const int* in_sizes, int n_in,
                              void* d_out, int out_size, void* d_ws, size_t ws_size,
                              hipStream_t stream) {
    const float* x     = (const float*)d_in[0];
    const float* Wt    = (const float*)d_in[1];
    const float* gamma = (const float*)d_in[2];
    const float* beta  = (const float*)d_in[3];
    float* out = (float*)d_out;

    // ws layout: [0,512) sc (128 floats); [4096, 4096+2*TOTAL*4) raw halves
    float* sc    = (float*)d_ws;
    float* raw01 = (float*)((char*)d_ws + 4096);

    adder_kernel<<<NB*14*8*2, 256, 0, stream>>>(x, Wt, raw01);
    stats_kernel<<<OC, 256, 0, stream>>>(raw01, gamma, beta, sc);
    bn_kernel<<<(TOTAL/4 + 255) / 256, 256, 0, stream>>>(raw01, sc, out);
}

// Round 9
// 74.471 us; speedup vs baseline: 1.2218x; 1.2218x over previous
//
#include <hip/hip_runtime.h>

#define NB   8
#define CIN  32
#define HH   28
#define WW   28
#define OC   64
#define HWSZ (HH*WW)            // 784
#define TOTAL (NB*OC*HWSZ)      // 401408
#define CNT  (NB*HWSZ)          // 6272 elements per channel for BN stats

#define KH   16                 // input channels per k-half
#define TROWS 4
#define TCOLS 30
#define TSZ  (KH*TROWS*TCOLS)   // 1920 floats = 7.7 KB LDS

#define CPW  2                  // output channels per wave (4 waves -> 8 ch/block)
// grid: n(8) x rowpair(14) x chgrp(8) x khalf(2) = 1792 blocks

// ---- adder: EXACT R0 structure (measured 78.07 us) — do not touch ----
__global__ __launch_bounds__(256) void adder_kernel(
    const float* __restrict__ x, const float* __restrict__ Wt,
    float* __restrict__ raw01)   // raw01 = two TOTAL-sized partial buffers
{
    __shared__ float xs[TSZ];
    const int t     = threadIdx.x;
    const int bid   = blockIdx.x;
    const int khalf = bid & 1;
    const int chgrp = (bid >> 1) & 7;
    const int rp    = (bid >> 4) % 14;
    const int n     = bid / (16 * 14);
    const int h0    = rp * 2;
    const int c0    = khalf * KH;

    // ---- stage x strip for channels c0..c0+15, rows h0-1..h0+2, cols -1..28 ----
    for (int i = t; i < TSZ; i += 256) {
        int cc  = i / (TROWS*TCOLS);
        int rem = i % (TROWS*TCOLS);
        int r   = rem / TCOLS;
        int col = rem % TCOLS;
        int hh  = h0 - 1 + r;
        int ww  = col - 1;
        float v = 0.0f;
        if (hh >= 0 && hh < HH && ww >= 0 && ww < WW)
            v = x[((n*CIN + (c0+cc))*HH + hh)*WW + ww];
        xs[i] = v;
    }
    __syncthreads();

    const int lane  = t & 63;
    const int g     = __builtin_amdgcn_readfirstlane(t >> 6); // wave id, uniform
    const bool valid = lane < 56;                 // 2 rows x 28 cols
    const int p     = valid ? lane : 0;
    const int pr    = p / WW;
    const int pw    = p % WW;
    const int o_base = chgrp*8 + g*CPW;

    float acc[CPW];
    #pragma unroll
    for (int oo = 0; oo < CPW; ++oo) acc[oo] = 0.0f;

    // current 3x3 patch in registers, prefetch next channel's patch
    float xr[9];
    {
        int b0 = pr*TCOLS + pw;   // cc = 0
        #pragma unroll
        for (int dr = 0; dr < 3; ++dr)
            #pragma unroll
            for (int dc = 0; dc < 3; ++dc)
                xr[dr*3+dc] = xs[b0 + dr*TCOLS + dc];
    }

    for (int cc = 0; cc < KH; ++cc) {
        float xn[9];
        if (cc + 1 < KH) {
            int b2 = ((cc+1)*TROWS + pr)*TCOLS + pw;
            #pragma unroll
            for (int dr = 0; dr < 3; ++dr)
                #pragma unroll
                for (int dc = 0; dc < 3; ++dc)
                    xn[dr*3+dc] = xs[b2 + dr*TCOLS + dc];
        }
        #pragma unroll
        for (int oo = 0; oo < CPW; ++oo) {
            const float* wp = Wt + ((o_base + oo)*CIN + (c0 + cc))*9; // uniform -> s_load
            #pragma unroll
            for (int j = 0; j < 9; ++j)
                acc[oo] += __builtin_fabsf(xr[j] - wp[j]);
        }
        if (cc + 1 < KH) {
            #pragma unroll
            for (int j = 0; j < 9; ++j) xr[j] = xn[j];
        }
    }

    if (valid) {
        float* rawh = raw01 + khalf * TOTAL;
        #pragma unroll
        for (int oo = 0; oo < CPW; ++oo)
            rawh[((n*OC + o_base + oo)*HH + (h0 + pr))*WW + pw] = -acc[oo];
    }
}

// ---- merged stats + BN apply: one block per channel ----
// Phase 1: stream r0+r1 for channel o into LDS while accumulating f64 sum/sumsq.
// Phase 2: finalize scale/shift, apply BN from LDS (raw read ONCE, one launch).
__global__ __launch_bounds__(256) void statsbn_kernel(
    const float* __restrict__ raw01,
    const float* __restrict__ gamma, const float* __restrict__ beta,
    float* __restrict__ out)
{
    __shared__ float vbuf[CNT];          // 6272 floats = 25 KB
    __shared__ double ls[4], ls2[4];
    __shared__ float sb[2];
    const int o = blockIdx.x;
    const int t = threadIdx.x;
    const float4* r0 = (const float4*)raw01;
    const float4* r1 = (const float4*)(raw01 + TOTAL);

    double s = 0.0, s2 = 0.0;
    #pragma unroll 2
    for (int i4 = t; i4 < CNT/4; i4 += 256) {     // 1568 float4s per channel
        int nn  = i4 / (HWSZ/4);
        int pos = i4 % (HWSZ/4);
        int idx = (nn*OC + o)*(HWSZ/4) + pos;
        float4 a = r0[idx];
        float4 b = r1[idx];
        float4 v;
        v.x = a.x + b.x; v.y = a.y + b.y; v.z = a.z + b.z; v.w = a.w + b.w;
        ((float4*)vbuf)[i4] = v;
        s  += (double)v.x + (double)v.y + (double)v.z + (double)v.w;
        s2 += (double)v.x*v.x + (double)v.y*v.y + (double)v.z*v.z + (double)v.w*v.w;
    }
    #pragma unroll
    for (int off = 32; off >= 1; off >>= 1) {
        s  += __shfl_xor(s,  off, 64);
        s2 += __shfl_xor(s2, off, 64);
    }
    const int lane = t & 63, w = t >> 6;
    if (lane == 0) { ls[w] = s; ls2[w] = s2; }
    __syncthreads();
    if (t == 0) {
        double S  = ls[0] + ls[1] + ls[2] + ls[3];
        double S2 = ls2[0] + ls2[1] + ls2[2] + ls2[3];
        double mean = S * (1.0 / CNT);
        double var  = S2 * (1.0 / CNT) - mean * mean;
        double inv  = 1.0 / sqrt(var + 1e-5);
        double scl  = (double)gamma[o] * inv;
        sb[0] = (float)scl;
        sb[1] = (float)((double)beta[o] - mean * scl);
    }
    __syncthreads();
    const float scl = sb[0], sh = sb[1];
    #pragma unroll 2
    for (int i4 = t; i4 < CNT/4; i4 += 256) {
        int nn  = i4 / (HWSZ/4);
        int pos = i4 % (HWSZ/4);
        int idx = (nn*OC + o)*(HWSZ/4) + pos;
        float4 v = ((const float4*)vbuf)[i4];
        float4 y;
        y.x = v.x * scl + sh;
        y.y = v.y * scl + sh;
        y.z = v.z * scl + sh;
        y.w = v.w * scl + sh;
        ((float4*)out)[idx] = y;
    }
}

extern "C" void kernel_launch(void* const* d_in, const int* in_sizes, int n_in,
                              void* d_out, int out_size, void* d_ws, size_t ws_size,
                              hipStream_t stream) {
    const float* x     = (const float*)d_in[0];
    const float* Wt    = (const float*)d_in[1];
    const float* gamma = (const float*)d_in[2];
    const float* beta  = (const float*)d_in[3];
    float* out = (float*)d_out;

    // ws layout: [4096, 4096+2*TOTAL*4) raw halves
    float* raw01 = (float*)((char*)d_ws + 4096);

    adder_kernel<<<NB*14*8*2, 256, 0, stream>>>(x, Wt, raw01);
    statsbn_kernel<<<OC, 256, 0, stream>>>(raw01, gamma, beta, out);
}